// Round 3
// baseline (242.990 us; speedup 1.0000x reference)
//
#include <hip/hip_runtime.h>

// Tuples (k=2): x (B=4, n=512, f=128) f32 -> out (B, n*n, 2f)
// out[b, i*n+j, c] = (c < f) ? x[b,i,c] : x[b,j,c-f]
//
// Write-BW bound: 1.07 GB written, 1 MB read (L2-resident).
// R3: 4x unroll (4 loads in flight before stores) + nontemporal stores
// via native ext_vector_type (HIP_vector_type float4 is rejected by the
// nontemporal builtin).

#define BATCH 4
#define NROW  512      // n
#define FEAT  128      // f

typedef float f32x4 __attribute__((ext_vector_type(4)));

__global__ void __launch_bounds__(256) tuples_bcast_kernel(
    const f32x4* __restrict__ x, f32x4* __restrict__ out)
{
    const unsigned total4   = (unsigned)BATCH << 24;      // 67,108,864
    const unsigned nthreads = gridDim.x * blockDim.x;     // 524,288
    const unsigned sweep    = nthreads * 4u;              // 2,097,152 (total4 % sweep == 0)

    for (unsigned idx0 = blockIdx.x * blockDim.x + threadIdx.x;
         idx0 < total4; idx0 += sweep)
    {
        f32x4    v[4];
        unsigned id[4];
        #pragma unroll
        for (int u = 0; u < 4; ++u) {
            unsigned i = idx0 + (unsigned)u * nthreads;   // stays lane-coalesced
            id[u] = i;
            unsigned c4 = i & 63u;                        // float4 slot in output row
            unsigned t  = (i >> 6) & ((NROW * NROW) - 1u);// tuple index i*n + j
            unsigned b  = i >> 24;                        // batch
            unsigned row = (c4 < 32u) ? (t >> 9) : (t & (NROW - 1u));
            v[u] = x[(b << 14) + (row << 5) + (c4 & 31u)];
        }
        #pragma unroll
        for (int u = 0; u < 4; ++u)
            __builtin_nontemporal_store(v[u], &out[id[u]]);
    }
}

extern "C" void kernel_launch(void* const* d_in, const int* in_sizes, int n_in,
                              void* d_out, int out_size, void* d_ws, size_t ws_size,
                              hipStream_t stream)
{
    const f32x4* x = (const f32x4*)d_in[0];
    f32x4* out = (f32x4*)d_out;
    tuples_bcast_kernel<<<2048, 256, 0, stream>>>(x, out);
}

// Round 4
// 202.928 us; speedup vs baseline: 1.1974x; 1.1974x over previous
//
#include <hip/hip_runtime.h>

// Tuples (k=2): x (B=4, n=512, f=128) f32 -> out (B, n*n, 2f)
// out[b, i*n+j, c] = (c < f) ? x[b,i,c] : x[b,j,c-f]
//
// R4 theory: stores increment vmcnt; a load->store loop's s_waitcnt vmcnt(0)
// drains prior stores each iteration, capping store pipelining (R1=5.1 TB/s,
// fill kernel=6.5 TB/s pure-store). Fix: stage inputs in LDS once per WG,
// then the hot loop is ds_read (lgkmcnt) -> global_store: the store stream
// is never waited on, matching the fill kernel's structure.
//
// WG = (b, i, j-block of 64 rows): stages 33 KB LDS, writes contiguous 64 KB.

#define BATCH 4
#define NROW  512
#define FEAT  128            // 32 f32x4 per input row

typedef float f32x4 __attribute__((ext_vector_type(4)));

__global__ void __launch_bounds__(256) tuples_lds_kernel(
    const f32x4* __restrict__ x, f32x4* __restrict__ out)
{
    __shared__ f32x4 lds[32 + 64 * 32];      // [0,32): row i; [32,2080): 64 j-rows

    const unsigned bid = blockIdx.x;          // 16384 blocks
    const unsigned jb  = bid & 7u;            // j-block (64 rows each)
    const unsigned i   = (bid >> 3) & 511u;
    const unsigned b   = bid >> 12;
    const unsigned t   = threadIdx.x;         // 256 threads

    // ---- stage: 64 j-rows = 2048 contiguous f32x4 (32 KB), plus row i ----
    const f32x4* src = x + (b << 14) + (jb << 11);   // rows jb*64 .. jb*64+63
    #pragma unroll
    for (int k = 0; k < 8; ++k)
        lds[32u + t + ((unsigned)k << 8)] = src[t + ((unsigned)k << 8)];
    if (t < 32u)
        lds[t] = x[(b << 14) + (i << 5) + t];
    __syncthreads();

    // ---- store loop: pure stores, no vmcnt waits ----
    const unsigned c4 = t & 63u;              // f32x4 slot within output row (fixed per thread)
    const unsigned r0 = t >> 6;               // starting local row (0..3)
    // LDS index: first half of row -> row i; second half -> j-row r
    const unsigned lbase = (c4 < 32u) ? c4 : (32u + (r0 << 5) + (c4 - 32u));
    const unsigned linc  = (c4 < 32u) ? 0u : 128u;   // advance 4 rows per iteration

    f32x4* o = out + ((size_t)b << 24) + ((size_t)((i << 9) + (jb << 6)) << 6) + t;
    #pragma unroll
    for (unsigned k = 0; k < 16; ++k)
        o[k << 8] = lds[lbase + k * linc];
}

extern "C" void kernel_launch(void* const* d_in, const int* in_sizes, int n_in,
                              void* d_out, int out_size, void* d_ws, size_t ws_size,
                              hipStream_t stream)
{
    const f32x4* x = (const f32x4*)d_in[0];
    f32x4* out = (f32x4*)d_out;
    tuples_lds_kernel<<<BATCH * NROW * 8, 256, 0, stream>>>(x, out);
}

// Round 5
// 196.246 us; speedup vs baseline: 1.2382x; 1.0341x over previous
//
#include <hip/hip_runtime.h>

// Tuples (k=2): x (B=4, n=512, f=128) f32 -> out (B, n*n, 2f)
// out[b, i*n+j, c] = (c < f) ? x[b,i,c] : x[b,j,c-f]
//
// R5: amortize staging. WG = (b, i-block of 8, j-block of 32):
//   stage 20 KB LDS (32 j-rows + 8 i-rows)  -> 8 WG/CU (160 KB exact)
//   store 256 KB (64 stores/thread), i-half from registers vi[8],
//   j-half via one broadcast ds_read per 8 stores, cndmask select.
// Store stream never waits on vmcnt; staging is ~7% of per-WG work.

#define BATCH 4
#define NROW  512
#define IB    8     // i-rows per WG
#define JB    32    // j-rows per WG

typedef float f32x4 __attribute__((ext_vector_type(4)));

__global__ void __launch_bounds__(256) tuples_lds8_kernel(
    const f32x4* __restrict__ x, f32x4* __restrict__ out)
{
    __shared__ f32x4 lds_j[JB * 32];   // 16 KB: 32 j-rows
    __shared__ f32x4 lds_i[IB * 32];   //  4 KB: 8 i-rows

    const unsigned bid = blockIdx.x;          // 4096 blocks
    const unsigned jb  = bid & 15u;           // j-block (32 rows)
    const unsigned ib  = (bid >> 4) & 63u;    // i-block (8 rows)
    const unsigned b   = bid >> 10;           // batch
    const unsigned t   = threadIdx.x;         // 256 threads

    // ---- stage ----
    const f32x4* srcj = x + (b << 14) + (jb << 10);   // 32 j-rows = 1024 f32x4
    #pragma unroll
    for (int q = 0; q < 4; ++q)
        lds_j[t + ((unsigned)q << 8)] = srcj[t + ((unsigned)q << 8)];
    lds_i[t] = x[(b << 14) + (ib << 8) + t];          // 8 i-rows = 256 f32x4
    __syncthreads();

    // ---- per-thread constants ----
    const unsigned c4  = t & 63u;             // output f32x4 slot (0..63)
    const unsigned r0  = t >> 6;              // wave id = starting j-row (0..3)
    const unsigned cs  = c4 & 31u;            // source column slot
    const bool     ihalf = (c4 < 32u);

    f32x4 vi[IB];
    #pragma unroll
    for (int il = 0; il < IB; ++il)
        vi[il] = lds_i[((unsigned)il << 5) | cs];

    // out f32x4 index = (b<<24) | (i<<15) | (jb<<11) | (jl<<6) | c4,  i = ib*8+il
    f32x4* o = out + ((size_t)b << 24) + ((size_t)ib << 18)
                   + ((size_t)jb << 11) + ((size_t)r0 << 6) + c4;

    // ---- store loop: 8 k-steps x 8 il-stores ----
    #pragma unroll
    for (unsigned k = 0; k < JB / 4; ++k) {
        const unsigned jl = r0 + (k << 2);              // uniform per wave
        const f32x4 vj = lds_j[(jl << 5) | cs];         // 2-lane broadcast, conflict-free
        f32x4* ok = o + ((size_t)k << 8);
        #pragma unroll
        for (int il = 0; il < IB; ++il) {
            f32x4 v = ihalf ? vi[il] : vj;
            ok[(size_t)il << 15] = v;
        }
    }
}

extern "C" void kernel_launch(void* const* d_in, const int* in_sizes, int n_in,
                              void* d_out, int out_size, void* d_ws, size_t ws_size,
                              hipStream_t stream)
{
    const f32x4* x = (const f32x4*)d_in[0];
    f32x4* out = (f32x4*)d_out;
    tuples_lds8_kernel<<<BATCH * (NROW / IB) * (NROW / JB), 256, 0, stream>>>(x, out);
}